// Round 1
// baseline (539.971 us; speedup 1.0000x reference)
//
#include <hip/hip_runtime.h>
#include <hip/hip_bf16.h>
#include <stdint.h>

#define N_NODES 100000
#define N_EDGES 1280000
#define N_PAIRS 500000

// ----------------- CSR build -----------------
__global__ void hist_kernel(const int* __restrict__ dst, int* __restrict__ cnt, int E) {
  int t = blockIdx.x * blockDim.x + threadIdx.x;
  if (t < E) atomicAdd(&cnt[dst[t]], 1);
}

__global__ void block_sum_kernel(const int* __restrict__ cnt, int* __restrict__ bsum, int N) {
  int i = blockIdx.x * 1024 + threadIdx.x;
  int v = (i < N) ? cnt[i] : 0;
  #pragma unroll
  for (int off = 32; off > 0; off >>= 1) v += __shfl_down(v, off);
  if ((threadIdx.x & 63) == 0) atomicAdd(&bsum[blockIdx.x], v);
}

__global__ void scan_bsum_kernel(int* bsum, int* rowptr_end, int NB) {
  __shared__ int s[128];
  int t = threadIdx.x;
  int c = (t < NB) ? bsum[t] : 0;
  s[t] = c;
  __syncthreads();
  for (int off = 1; off < 128; off <<= 1) {
    int v = (t >= off) ? s[t - off] : 0;
    __syncthreads();
    s[t] += v;
    __syncthreads();
  }
  if (t < NB) bsum[t] = s[t] - c;       // exclusive block offsets
  if (t == 127) *rowptr_end = s[127];   // total == E
}

__global__ void scan_write_kernel(const int* __restrict__ cnt, const int* __restrict__ boff,
                                  int* __restrict__ rowptr, int* __restrict__ cursor, int N) {
  __shared__ int s[1024];
  int t = threadIdx.x;
  int i = blockIdx.x * 1024 + t;
  int c = (i < N) ? cnt[i] : 0;
  s[t] = c;
  __syncthreads();
  for (int off = 1; off < 1024; off <<= 1) {
    int v = (t >= off) ? s[t - off] : 0;
    __syncthreads();
    s[t] += v;
    __syncthreads();
  }
  if (i < N) {
    int val = boff[blockIdx.x] + s[t] - c;  // exclusive prefix
    rowptr[i] = val;
    cursor[i] = val;
  }
}

__global__ void fill_kernel(const int* __restrict__ src, const int* __restrict__ dst,
                            int* __restrict__ cursor, int* __restrict__ adj, int E) {
  int t = blockIdx.x * blockDim.x + threadIdx.x;
  if (t < E) {
    int pos = atomicAdd(&cursor[dst[t]], 1);
    adj[pos] = src[t];
  }
}

// ----------------- GEMM: C[M x 128] = A[M x 64] @ [B1 | B2] (each 64x64) -----------------
__global__ __launch_bounds__(256) void gemm_k64(
    const float* __restrict__ A, const float* __restrict__ B1, const float* __restrict__ B2,
    float* __restrict__ C, int M) {
  __shared__ float As[64][128];   // transposed: As[c][m]
  __shared__ float Bs[64][128];   // Bs[c][n]
  const int tid = threadIdx.x;
  const int m_base = blockIdx.x * 128;

  #pragma unroll
  for (int it = 0; it < 8; ++it) {
    int q = tid + it * 256;       // 0..2047
    int row = q >> 4;             // 0..127
    int cq = q & 15;              // quad of columns
    float4 v = make_float4(0.f, 0.f, 0.f, 0.f);
    if (m_base + row < M) v = *(const float4*)&A[(size_t)(m_base + row) * 64 + cq * 4];
    As[cq * 4 + 0][row] = v.x;
    As[cq * 4 + 1][row] = v.y;
    As[cq * 4 + 2][row] = v.z;
    As[cq * 4 + 3][row] = v.w;
  }
  #pragma unroll
  for (int it = 0; it < 8; ++it) {
    int q = tid + it * 256;       // 0..2047
    int c = q >> 5;               // 0..63
    int nq = q & 31;
    int n = nq * 4;
    const float* s = (n < 64) ? (B1 + c * 64 + n) : (B2 + c * 64 + (n - 64));
    *(float4*)&Bs[c][n] = *(const float4*)s;
  }
  __syncthreads();

  const int w = tid >> 6, l = tid & 63;
  const int m0 = ((w >> 1) * 8 + (l >> 3)) * 8;
  const int n0 = ((w & 1) * 8 + (l & 7)) * 8;

  float acc[8][8];
  #pragma unroll
  for (int i = 0; i < 8; ++i)
    #pragma unroll
    for (int j = 0; j < 8; ++j) acc[i][j] = 0.f;

  #pragma unroll 4
  for (int c = 0; c < 64; ++c) {
    float4 a0 = *(const float4*)&As[c][m0];
    float4 a1 = *(const float4*)&As[c][m0 + 4];
    float4 b0 = *(const float4*)&Bs[c][n0];
    float4 b1 = *(const float4*)&Bs[c][n0 + 4];
    float a[8] = {a0.x, a0.y, a0.z, a0.w, a1.x, a1.y, a1.z, a1.w};
    float b[8] = {b0.x, b0.y, b0.z, b0.w, b1.x, b1.y, b1.z, b1.w};
    #pragma unroll
    for (int i = 0; i < 8; ++i)
      #pragma unroll
      for (int j = 0; j < 8; ++j)
        acc[i][j] = fmaf(a[i], b[j], acc[i][j]);
  }

  #pragma unroll
  for (int i = 0; i < 8; ++i) {
    int gr = m_base + m0 + i;
    if (gr < M) {
      float4 o0 = make_float4(acc[i][0], acc[i][1], acc[i][2], acc[i][3]);
      float4 o1 = make_float4(acc[i][4], acc[i][5], acc[i][6], acc[i][7]);
      *(float4*)&C[(size_t)gr * 128 + n0] = o0;
      *(float4*)&C[(size_t)gr * 128 + n0 + 4] = o1;
    }
  }
}

// ----------------- aggregation: H[i] = relu(mean_j QP[j][0:64] + QP[i][64:128] + bias) --------
__global__ __launch_bounds__(256) void agg_kernel(
    const float* __restrict__ QP, const int* __restrict__ rowptr, const int* __restrict__ adj,
    const float* __restrict__ bias, float* __restrict__ H, int N) {
  int node = blockIdx.x * 4 + (threadIdx.x >> 6);
  int lane = threadIdx.x & 63;
  if (node >= N) return;
  int r0 = rowptr[node], r1 = rowptr[node + 1];
  float acc = 0.f;
  for (int base = r0; base < r1; base += 64) {
    int nb = min(64, r1 - base);
    int idx = (lane < nb) ? adj[base + lane] : 0;
    for (int k = 0; k < nb; ++k) {
      int j = __shfl(idx, k);
      acc += QP[(size_t)j * 128 + lane];
    }
  }
  float cnt = (float)(r1 - r0);
  float mean = acc / fmaxf(cnt, 1.f);
  float v = mean + QP[(size_t)node * 128 + 64 + lane] + bias[lane];
  H[(size_t)node * 64 + lane] = fmaxf(v, 0.f);
}

// ----------------- pair readout: out[p] = Wr2 . relu(T[a][0:64]+T[b][64:128]+br1) + br2 -------
__global__ __launch_bounds__(256) void pair_kernel(
    const float* __restrict__ T, const int* __restrict__ pairs,
    const float* __restrict__ br1, const float* __restrict__ Wr2, const float* __restrict__ br2,
    float* __restrict__ out, int P) {
  int p = blockIdx.x * 4 + (threadIdx.x >> 6);
  int lane = threadIdx.x & 63;
  if (p >= P) return;
  int a = pairs[2 * p];
  int b = pairs[2 * p + 1];
  float z = T[(size_t)a * 128 + lane] + T[(size_t)b * 128 + 64 + lane] + br1[lane];
  z = fmaxf(z, 0.f);
  float v = z * Wr2[lane];
  #pragma unroll
  for (int off = 32; off > 0; off >>= 1) v += __shfl_down(v, off);
  if (lane == 0) out[p] = v + br2[0];
}

extern "C" void kernel_launch(void* const* d_in, const int* in_sizes, int n_in,
                              void* d_out, int out_size, void* d_ws, size_t ws_size,
                              hipStream_t stream) {
  const float* x   = (const float*)d_in[0];
  const int*   ei  = (const int*)d_in[1];
  const int* pairs = (const int*)d_in[2];
  const float* W1l = (const float*)d_in[3];
  const float* b1l = (const float*)d_in[4];
  const float* W1r = (const float*)d_in[5];
  const float* W2l = (const float*)d_in[6];
  const float* b2l = (const float*)d_in[7];
  const float* W2r = (const float*)d_in[8];
  const float* Wr1 = (const float*)d_in[9];
  const float* br1 = (const float*)d_in[10];
  const float* Wr2 = (const float*)d_in[11];
  const float* br2 = (const float*)d_in[12];
  float* out = (float*)d_out;

  const int N = N_NODES, E = N_EDGES, P = N_PAIRS;
  const int* srcI = ei;        // edge_index[0]
  const int* dstI = ei + E;    // edge_index[1]

  char* w = (char*)d_ws;
  int* rowptr = (int*)w;  w += (size_t)(N + 1) * 4;
  int* cursor = (int*)w;  w += (size_t)(N + 1) * 4;   // doubles as cnt
  int* bsum   = (int*)w;  w += 128 * 4;
  int* adj    = (int*)w;  w += (size_t)E * 4;
  w = (char*)(((uintptr_t)w + 15) & ~(uintptr_t)15);
  float* QP = (float*)w;  w += (size_t)N * 128 * 4;   // per-layer [Q|P], also T
  float* H  = (float*)w;  w += (size_t)N * 64 * 4;    // h1 then h2 (in-place swap via QP)

  // zero cnt (=cursor) and bsum (contiguous)
  hipMemsetAsync(cursor, 0, ((size_t)(N + 1) + 128) * 4, stream);

  hist_kernel<<<(E + 255) / 256, 256, 0, stream>>>(dstI, cursor, E);
  const int NB = (N + 1023) / 1024;  // 98
  block_sum_kernel<<<NB, 1024, 0, stream>>>(cursor, bsum, N);
  scan_bsum_kernel<<<1, 128, 0, stream>>>(bsum, rowptr + N, NB);
  scan_write_kernel<<<NB, 1024, 0, stream>>>(cursor, bsum, rowptr, cursor, N);
  fill_kernel<<<(E + 255) / 256, 256, 0, stream>>>(srcI, dstI, cursor, adj, E);

  const int GB = (N + 127) / 128;
  // layer 1: QP = x @ [W1l | W1r];  H = relu(mean-agg(Q) + P + b1l)
  gemm_k64<<<GB, 256, 0, stream>>>(x, W1l, W1r, QP, N);
  agg_kernel<<<(N + 3) / 4, 256, 0, stream>>>(QP, rowptr, adj, b1l, H, N);
  // layer 2
  gemm_k64<<<GB, 256, 0, stream>>>(H, W2l, W2r, QP, N);
  agg_kernel<<<(N + 3) / 4, 256, 0, stream>>>(QP, rowptr, adj, b2l, H, N);
  // readout precompute: T = H @ [Wr1_top | Wr1_bot]
  gemm_k64<<<GB, 256, 0, stream>>>(H, Wr1, Wr1 + 64 * 64, QP, N);
  // pairs
  pair_kernel<<<(P + 3) / 4, 256, 0, stream>>>(QP, pairs, br1, Wr2, br2, out, P);
}

// Round 2
// 427.045 us; speedup vs baseline: 1.2644x; 1.2644x over previous
//
#include <hip/hip_runtime.h>
#include <hip/hip_bf16.h>
#include <stdint.h>

#define N_NODES 100000
#define N_EDGES 1280000
#define N_PAIRS 500000

// ----------------- CSR build -----------------
__global__ void hist_kernel(const int* __restrict__ dst, int* __restrict__ cnt, int E) {
  int t = blockIdx.x * blockDim.x + threadIdx.x;
  if (t < E) atomicAdd(&cnt[dst[t]], 1);
}

__global__ void block_sum_kernel(const int* __restrict__ cnt, int* __restrict__ bsum, int N) {
  int i = blockIdx.x * 1024 + threadIdx.x;
  int v = (i < N) ? cnt[i] : 0;
  #pragma unroll
  for (int off = 32; off > 0; off >>= 1) v += __shfl_down(v, off);
  if ((threadIdx.x & 63) == 0) atomicAdd(&bsum[blockIdx.x], v);
}

__global__ void scan_bsum_kernel(int* bsum, int* rowptr_end, int NB) {
  __shared__ int s[128];
  int t = threadIdx.x;
  int c = (t < NB) ? bsum[t] : 0;
  s[t] = c;
  __syncthreads();
  for (int off = 1; off < 128; off <<= 1) {
    int v = (t >= off) ? s[t - off] : 0;
    __syncthreads();
    s[t] += v;
    __syncthreads();
  }
  if (t < NB) bsum[t] = s[t] - c;       // exclusive block offsets
  if (t == 127) *rowptr_end = s[127];   // total == E
}

__global__ void scan_write_kernel(const int* __restrict__ cnt, const int* __restrict__ boff,
                                  int* __restrict__ rowptr, int* __restrict__ cursor, int N) {
  __shared__ int s[1024];
  int t = threadIdx.x;
  int i = blockIdx.x * 1024 + t;
  int c = (i < N) ? cnt[i] : 0;
  s[t] = c;
  __syncthreads();
  for (int off = 1; off < 1024; off <<= 1) {
    int v = (t >= off) ? s[t - off] : 0;
    __syncthreads();
    s[t] += v;
    __syncthreads();
  }
  if (i < N) {
    int val = boff[blockIdx.x] + s[t] - c;  // exclusive prefix
    rowptr[i] = val;
    cursor[i] = val;
  }
}

__global__ void fill_kernel(const int* __restrict__ src, const int* __restrict__ dst,
                            int* __restrict__ cursor, int* __restrict__ adj, int E) {
  int t = blockIdx.x * blockDim.x + threadIdx.x;
  if (t < E) {
    int pos = atomicAdd(&cursor[dst[t]], 1);
    adj[pos] = src[t];
  }
}

// ----------------- GEMM: [C1 | C2][M x 64] = A[M x 64] @ [B1 | B2] (each 64x64) -----------------
__global__ __launch_bounds__(256) void gemm_k64(
    const float* __restrict__ A, const float* __restrict__ B1, const float* __restrict__ B2,
    float* __restrict__ C1, float* __restrict__ C2, int M) {
  __shared__ float As[64][128];   // transposed: As[c][m]
  __shared__ float Bs[64][128];   // Bs[c][n]
  const int tid = threadIdx.x;
  const int m_base = blockIdx.x * 128;

  #pragma unroll
  for (int it = 0; it < 8; ++it) {
    int q = tid + it * 256;       // 0..2047
    int row = q >> 4;             // 0..127
    int cq = q & 15;              // quad of columns
    float4 v = make_float4(0.f, 0.f, 0.f, 0.f);
    if (m_base + row < M) v = *(const float4*)&A[(size_t)(m_base + row) * 64 + cq * 4];
    As[cq * 4 + 0][row] = v.x;
    As[cq * 4 + 1][row] = v.y;
    As[cq * 4 + 2][row] = v.z;
    As[cq * 4 + 3][row] = v.w;
  }
  #pragma unroll
  for (int it = 0; it < 8; ++it) {
    int q = tid + it * 256;       // 0..2047
    int c = q >> 5;               // 0..63
    int nq = q & 31;
    int n = nq * 4;
    const float* s = (n < 64) ? (B1 + c * 64 + n) : (B2 + c * 64 + (n - 64));
    *(float4*)&Bs[c][n] = *(const float4*)s;
  }
  __syncthreads();

  const int w = tid >> 6, l = tid & 63;
  const int m0 = ((w >> 1) * 8 + (l >> 3)) * 8;
  const int n0 = ((w & 1) * 8 + (l & 7)) * 8;

  float acc[8][8];
  #pragma unroll
  for (int i = 0; i < 8; ++i)
    #pragma unroll
    for (int j = 0; j < 8; ++j) acc[i][j] = 0.f;

  #pragma unroll 4
  for (int c = 0; c < 64; ++c) {
    float4 a0 = *(const float4*)&As[c][m0];
    float4 a1 = *(const float4*)&As[c][m0 + 4];
    float4 b0 = *(const float4*)&Bs[c][n0];
    float4 b1 = *(const float4*)&Bs[c][n0 + 4];
    float a[8] = {a0.x, a0.y, a0.z, a0.w, a1.x, a1.y, a1.z, a1.w};
    float b[8] = {b0.x, b0.y, b0.z, b0.w, b1.x, b1.y, b1.z, b1.w};
    #pragma unroll
    for (int i = 0; i < 8; ++i)
      #pragma unroll
      for (int j = 0; j < 8; ++j)
        acc[i][j] = fmaf(a[i], b[j], acc[i][j]);
  }

  float* Cout = (n0 < 64) ? C1 : C2;
  const int nn = (n0 < 64) ? n0 : (n0 - 64);
  #pragma unroll
  for (int i = 0; i < 8; ++i) {
    int gr = m_base + m0 + i;
    if (gr < M) {
      float4 o0 = make_float4(acc[i][0], acc[i][1], acc[i][2], acc[i][3]);
      float4 o1 = make_float4(acc[i][4], acc[i][5], acc[i][6], acc[i][7]);
      *(float4*)&C1[0];  // no-op to keep types; real stores below
      *(float4*)&Cout[(size_t)gr * 64 + nn] = o0;
      *(float4*)&Cout[(size_t)gr * 64 + nn + 4] = o1;
    }
  }
}

// ----------------- aggregation: H[i] = relu(mean_j Q[j] + P[i] + bias) --------
// lane = 4 neighbor slots x 16 channel-quads; one wave per node.
__global__ __launch_bounds__(256) void agg_kernel(
    const float* __restrict__ Q, const float* __restrict__ P,
    const int* __restrict__ rowptr, const int* __restrict__ adj,
    const float* __restrict__ bias, float* __restrict__ H, int N) {
  int node = blockIdx.x * 4 + (threadIdx.x >> 6);
  if (node >= N) return;
  int lane = threadIdx.x & 63;
  int g = lane >> 4;          // neighbor slot 0..3
  int c4 = (lane & 15) * 4;   // channel quad base
  int r0 = rowptr[node], r1 = rowptr[node + 1];

  float4 acc0 = make_float4(0.f, 0.f, 0.f, 0.f);
  float4 acc1 = make_float4(0.f, 0.f, 0.f, 0.f);
  int base = r0;
  for (; base + 8 <= r1; base += 8) {
    int j0 = adj[base + g];
    int j1 = adj[base + 4 + g];
    float4 v0 = *(const float4*)&Q[(size_t)j0 * 64 + c4];
    float4 v1 = *(const float4*)&Q[(size_t)j1 * 64 + c4];
    acc0.x += v0.x; acc0.y += v0.y; acc0.z += v0.z; acc0.w += v0.w;
    acc1.x += v1.x; acc1.y += v1.y; acc1.z += v1.z; acc1.w += v1.w;
  }
  if (base + g < r1) {
    int j = adj[base + g];
    float4 v = *(const float4*)&Q[(size_t)j * 64 + c4];
    acc0.x += v.x; acc0.y += v.y; acc0.z += v.z; acc0.w += v.w;
  }
  if (base + 4 + g < r1) {
    int j = adj[base + 4 + g];
    float4 v = *(const float4*)&Q[(size_t)j * 64 + c4];
    acc1.x += v.x; acc1.y += v.y; acc1.z += v.z; acc1.w += v.w;
  }
  acc0.x += acc1.x; acc0.y += acc1.y; acc0.z += acc1.z; acc0.w += acc1.w;

  // combine 4 neighbor slots: lanes +32, then +16
  acc0.x += __shfl_down(acc0.x, 32); acc0.y += __shfl_down(acc0.y, 32);
  acc0.z += __shfl_down(acc0.z, 32); acc0.w += __shfl_down(acc0.w, 32);
  acc0.x += __shfl_down(acc0.x, 16); acc0.y += __shfl_down(acc0.y, 16);
  acc0.z += __shfl_down(acc0.z, 16); acc0.w += __shfl_down(acc0.w, 16);

  if (lane < 16) {
    float inv = 1.f / fmaxf((float)(r1 - r0), 1.f);
    float4 p = *(const float4*)&P[(size_t)node * 64 + c4];
    float4 b = *(const float4*)&bias[c4];
    float4 o;
    o.x = fmaxf(acc0.x * inv + p.x + b.x, 0.f);
    o.y = fmaxf(acc0.y * inv + p.y + b.y, 0.f);
    o.z = fmaxf(acc0.z * inv + p.z + b.z, 0.f);
    o.w = fmaxf(acc0.w * inv + p.w + b.w, 0.f);
    *(float4*)&H[(size_t)node * 64 + c4] = o;
  }
}

// ----------------- pair readout: out[p] = Wr2 . relu(U[a]+V[b]+br1) + br2 -------
// 2 pairs per wave: lane = {pair slot} x {side} x {channel quad}
__global__ __launch_bounds__(256) void pair_kernel(
    const float* __restrict__ U, const float* __restrict__ V, const int* __restrict__ pairs,
    const float* __restrict__ br1, const float* __restrict__ Wr2, const float* __restrict__ br2,
    float* __restrict__ out, int P) {
  int wave = blockIdx.x * 4 + (threadIdx.x >> 6);
  int lane = threadIdx.x & 63;
  int h = lane >> 5;           // pair slot 0/1
  int sub = lane & 31;
  int side = sub >> 4;         // 0 = a (U), 1 = b (V)
  int c4 = (sub & 15) * 4;
  int p = wave * 2 + h;
  if (p >= P) return;

  int node = pairs[2 * p + side];
  const float* T = side ? V : U;
  float4 t = *(const float4*)&T[(size_t)node * 64 + c4];

  // combine sides within each 32-lane half
  t.x += __shfl_down(t.x, 16); t.y += __shfl_down(t.y, 16);
  t.z += __shfl_down(t.z, 16); t.w += __shfl_down(t.w, 16);

  float r = 0.f;
  if (side == 0) {
    float4 b = *(const float4*)&br1[c4];
    float4 w = *(const float4*)&Wr2[c4];
    float zx = fmaxf(t.x + b.x, 0.f);
    float zy = fmaxf(t.y + b.y, 0.f);
    float zz = fmaxf(t.z + b.z, 0.f);
    float zw = fmaxf(t.w + b.w, 0.f);
    r = zx * w.x + zy * w.y + zz * w.z + zw * w.w;
  }
  r += __shfl_xor(r, 1);
  r += __shfl_xor(r, 2);
  r += __shfl_xor(r, 4);
  r += __shfl_xor(r, 8);
  if (sub == 0) out[p] = r + br2[0];
}

extern "C" void kernel_launch(void* const* d_in, const int* in_sizes, int n_in,
                              void* d_out, int out_size, void* d_ws, size_t ws_size,
                              hipStream_t stream) {
  const float* x   = (const float*)d_in[0];
  const int*   ei  = (const int*)d_in[1];
  const int* pairs = (const int*)d_in[2];
  const float* W1l = (const float*)d_in[3];
  const float* b1l = (const float*)d_in[4];
  const float* W1r = (const float*)d_in[5];
  const float* W2l = (const float*)d_in[6];
  const float* b2l = (const float*)d_in[7];
  const float* W2r = (const float*)d_in[8];
  const float* Wr1 = (const float*)d_in[9];
  const float* br1 = (const float*)d_in[10];
  const float* Wr2 = (const float*)d_in[11];
  const float* br2 = (const float*)d_in[12];
  float* out = (float*)d_out;

  const int N = N_NODES, E = N_EDGES, P = N_PAIRS;
  const int* srcI = ei;        // edge_index[0]
  const int* dstI = ei + E;    // edge_index[1]

  char* w = (char*)d_ws;
  int* rowptr = (int*)w;  w += (size_t)(N + 1) * 4;
  int* cursor = (int*)w;  w += (size_t)(N + 1) * 4;   // doubles as cnt
  int* bsum   = (int*)w;  w += 128 * 4;
  int* adj    = (int*)w;  w += (size_t)E * 4;
  w = (char*)(((uintptr_t)w + 255) & ~(uintptr_t)255);
  float* Q  = (float*)w;  w += (size_t)N * 64 * 4;    // gather table (also U)
  float* Pt = (float*)w;  w += (size_t)N * 64 * 4;    // self-transform (also V)
  float* H  = (float*)w;  w += (size_t)N * 64 * 4;    // hidden state (reused in place)

  hipMemsetAsync(cursor, 0, ((size_t)(N + 1) + 128) * 4, stream);

  hist_kernel<<<(E + 255) / 256, 256, 0, stream>>>(dstI, cursor, E);
  const int NB = (N + 1023) / 1024;  // 98
  block_sum_kernel<<<NB, 1024, 0, stream>>>(cursor, bsum, N);
  scan_bsum_kernel<<<1, 128, 0, stream>>>(bsum, rowptr + N, NB);
  scan_write_kernel<<<NB, 1024, 0, stream>>>(cursor, bsum, rowptr, cursor, N);
  fill_kernel<<<(E + 255) / 256, 256, 0, stream>>>(srcI, dstI, cursor, adj, E);

  const int GB = (N + 127) / 128;
  // layer 1: [Q|P] = x @ [W1l | W1r];  H = relu(mean-agg(Q) + P + b1l)
  gemm_k64<<<GB, 256, 0, stream>>>(x, W1l, W1r, Q, Pt, N);
  agg_kernel<<<(N + 3) / 4, 256, 0, stream>>>(Q, Pt, rowptr, adj, b1l, H, N);
  // layer 2
  gemm_k64<<<GB, 256, 0, stream>>>(H, W2l, W2r, Q, Pt, N);
  agg_kernel<<<(N + 3) / 4, 256, 0, stream>>>(Q, Pt, rowptr, adj, b2l, H, N);
  // readout precompute: [U|V] = H @ [Wr1_top | Wr1_bot]
  gemm_k64<<<GB, 256, 0, stream>>>(H, Wr1, Wr1 + 64 * 64, Q, Pt, N);
  // pairs
  pair_kernel<<<(P + 127) / 128 * 32, 256, 0, stream>>>(Q, Pt, pairs, br1, Wr2, br2, out, P);
}